// Round 13
// baseline (1272.813 us; speedup 1.0000x reference)
//
#include <hip/hip_runtime.h>

#define NL 5      // num_layers (fixed by setup_inputs)
#define SS 6      // num_layers + 1
#define DD 128
#define GG 16     // NUM_GRAPHS
#define GNB 32    // nodes per block in GRU kernel
#define APB 8     // nodes per block in attention kernel
#define SCB 1024  // scan chunk

typedef __bf16 bf16x8 __attribute__((ext_vector_type(8)));
typedef float f32x4 __attribute__((ext_vector_type(4)));
typedef unsigned short ushort_t;

__device__ __forceinline__ float bf2f(unsigned int u) {
  union { unsigned int i; float f; } c; c.i = u << 16; return c.f;
}
__device__ __forceinline__ ushort_t f2bf(float f) {
  union { __bf16 b; ushort_t u; } c; c.b = (__bf16)f;  // HW v_cvt, RNE
  return c.u;
}

// ---------------- CSR build ----------------
__global__ void k_deg(const int* __restrict__ ei, int E, int* __restrict__ deg) {
  int e = blockIdx.x * 256 + threadIdx.x;
  if (e < E) atomicAdd(&deg[ei[E + e]], 1);
}

__global__ void k_scan1(const int* __restrict__ deg, int* __restrict__ off,
                        int* __restrict__ bsum, int N) {
  __shared__ int tmp[SCB];
  int t = threadIdx.x, i = blockIdx.x * SCB + t;
  int v = (i < N) ? deg[i] : 0;
  tmp[t] = v; __syncthreads();
  for (int o = 1; o < SCB; o <<= 1) {
    int a = (t >= o) ? tmp[t - o] : 0;
    __syncthreads(); tmp[t] += a; __syncthreads();
  }
  if (i < N) off[i] = tmp[t] - v;   // local exclusive
  if (t == SCB - 1) bsum[blockIdx.x] = tmp[t];
}

__global__ void k_scan2(int* __restrict__ bsum, int nb) {
  __shared__ int tmp[SCB];
  int t = threadIdx.x;
  int v = (t < nb) ? bsum[t] : 0;
  tmp[t] = v; __syncthreads();
  for (int o = 1; o < SCB; o <<= 1) {
    int a = (t >= o) ? tmp[t - o] : 0;
    __syncthreads(); tmp[t] += a; __syncthreads();
  }
  if (t < nb) bsum[t] = tmp[t] - v;  // exclusive
}

// writes final offsets to BOTH off and cur; also fused k_bend (graph end boundaries)
__global__ void k_scan3(int* __restrict__ off, int* __restrict__ cur,
                        const int* __restrict__ bsum,
                        const int* __restrict__ batch, int* __restrict__ endp,
                        int N, int E) {
  int i = blockIdx.x * 256 + threadIdx.x;
  if (i < N) {
    int v = off[i] + bsum[i >> 10];
    off[i] = v;
    cur[i] = v;
    int b = batch[i];
    if (i == N - 1 || batch[i + 1] != b) endp[b] = i + 1;
  } else if (i == N) off[N] = E;
}

__global__ void k_fill(const int* __restrict__ ei, const float* __restrict__ norm, int E,
                       int* __restrict__ cur, int* __restrict__ csrs, float* __restrict__ csrn) {
  int e = blockIdx.x * 256 + threadIdx.x;
  if (e >= E) return;
  int s = ei[e], d = ei[E + e];
  int p = atomicAdd(&cur[d], 1);
  csrs[p] = s;
  csrn[p] = norm[e];
}

__global__ void k_cnt(const int* __restrict__ endp, int* __restrict__ cnt) {
  if (threadIdx.x == 0 && blockIdx.x == 0) {
    int prev = 0;
    for (int g = 0; g < GG; ++g) {
      int e = endp[g];
      if (e > prev) { cnt[g] = e - prev; prev = e; }
      else cnt[g] = 0;
    }
  }
}

// ---------------- weight conversion + B-fragment swizzle ----------------
// B-frag order: out[((ctg*4 + ks)*64 + lane)*8 + j] = W[ctg*16 + (lane&15)][ks*32 + ((lane>>4)<<3) + j]
__global__ void k_wconv(const float* __restrict__ wih, const float* __restrict__ whh,
                        const float* __restrict__ ipw, const float* __restrict__ ow,
                        const float* __restrict__ d1,
                        ushort_t* __restrict__ WB, ushort_t* __restrict__ WI,
                        ushort_t* __restrict__ WO, ushort_t* __restrict__ WD1) {
  int o = blockIdx.x * 256 + threadIdx.x;
  int seg, idx;
  if (o < 98304) { seg = 0; idx = o; }
  else if (o < 98304 + 49152) { seg = 1; idx = o - 98304; }
  else if (o < 98304 + 49152 + 16384) { seg = 2; idx = o - 98304 - 49152; }
  else if (o < 98304 + 49152 + 16384 + 8192) { seg = 3; idx = o - 98304 - 49152 - 16384; }
  else return;
  int j = idx & 7, l = (idx >> 3) & 63, ks = (idx >> 9) & 3, ctg = idx >> 11;
  int row = ctg * 16 + (l & 15);
  int col = ks * 32 + ((l >> 4) << 3) + j;
  float v;
  if (seg == 0) { v = (row < 384) ? wih[row * 128 + col] : whh[(row - 384) * 128 + col]; WB[idx] = f2bf(v); }
  else if (seg == 1) { WI[idx] = f2bf(ipw[row * 128 + col]); }
  else if (seg == 2) { WO[idx] = f2bf(ow[row * 128 + col]); }
  else { WD1[idx] = f2bf(d1[row * 128 + col]); }
}

// ---------------- encoder (2 dims/thread, dword stores) ----------------
__global__ void k_encode(const float* __restrict__ x, const float* __restrict__ ew,
                         ushort_t* __restrict__ HS, int N) {
  int idx = blockIdx.x * 256 + threadIdx.x;
  if (idx >= N * 64) return;
  int n = idx >> 6, d0 = (idx & 63) << 1;
  float xr[6];
#pragma unroll
  for (int k = 0; k < 6; ++k) xr[k] = x[n * 6 + k];
  float a0 = 0.f, a1 = 0.f;
#pragma unroll
  for (int k = 0; k < 6; ++k) {
    a0 += xr[k] * ew[d0 * 6 + k];
    a1 += xr[k] * ew[(d0 + 1) * 6 + k];
  }
  a0 = a0 > 0.f ? a0 : 0.01f * a0;
  a1 = a1 > 0.f ? a1 : 0.01f * a1;
  unsigned int pk = (unsigned int)f2bf(a0) | ((unsigned int)f2bf(a1) << 16);
  *(unsigned int*)&HS[((size_t)n * SS) * DD + d0] = pk;
}

// ---------------- aggregation: 4 nodes/wave (16 lanes x 8 bf16 via uint4), 8-deep ILP
// block 0 also zeroes SUMS+SUMSQ (contiguous, 2*GG*DD floats) for this layer
__global__ __launch_bounds__(256) void k_agg(const ushort_t* __restrict__ HS, int l,
    const int* __restrict__ off, const int* __restrict__ csrs, const float* __restrict__ csrn,
    ushort_t* __restrict__ AGG, float* __restrict__ SUMS, int N) {
  if (blockIdx.x == 0) {
    for (int i = threadIdx.x; i < 2 * GG * DD; i += 256) SUMS[i] = 0.f;
  }
  int n = blockIdx.x * 16 + (threadIdx.x >> 4);
  if (n >= N) return;
  int lane16 = threadIdx.x & 15;
  int p0 = off[n], p1 = off[n + 1];
  float a0 = 0.f, a1 = 0.f, a2 = 0.f, a3 = 0.f, a4 = 0.f, a5 = 0.f, a6 = 0.f, a7 = 0.f;
  const ushort_t* base = HS + l * DD + lane16 * 8;
  int p = p0;
  for (; p + 8 <= p1; p += 8) {
    int s[8]; float w[8]; uint4 u[8];
#pragma unroll
    for (int q = 0; q < 8; ++q) { s[q] = csrs[p + q]; w[q] = csrn[p + q]; }
#pragma unroll
    for (int q = 0; q < 8; ++q) u[q] = *(const uint4*)(base + (size_t)s[q] * (SS * DD));
#pragma unroll
    for (int q = 0; q < 8; ++q) {
      a0 += w[q] * bf2f(u[q].x & 0xffffu);
      a1 += w[q] * bf2f(u[q].x >> 16);
      a2 += w[q] * bf2f(u[q].y & 0xffffu);
      a3 += w[q] * bf2f(u[q].y >> 16);
      a4 += w[q] * bf2f(u[q].z & 0xffffu);
      a5 += w[q] * bf2f(u[q].z >> 16);
      a6 += w[q] * bf2f(u[q].w & 0xffffu);
      a7 += w[q] * bf2f(u[q].w >> 16);
    }
  }
  for (; p < p1; ++p) {
    int s0 = csrs[p];
    float w0 = csrn[p];
    uint4 u0 = *(const uint4*)(base + (size_t)s0 * (SS * DD));
    a0 += w0 * bf2f(u0.x & 0xffffu);
    a1 += w0 * bf2f(u0.x >> 16);
    a2 += w0 * bf2f(u0.y & 0xffffu);
    a3 += w0 * bf2f(u0.y >> 16);
    a4 += w0 * bf2f(u0.z & 0xffffu);
    a5 += w0 * bf2f(u0.z >> 16);
    a6 += w0 * bf2f(u0.w & 0xffffu);
    a7 += w0 * bf2f(u0.w >> 16);
  }
  uint4 pk;
  pk.x = (unsigned int)f2bf(a0) | ((unsigned int)f2bf(a1) << 16);
  pk.y = (unsigned int)f2bf(a2) | ((unsigned int)f2bf(a3) << 16);
  pk.z = (unsigned int)f2bf(a4) | ((unsigned int)f2bf(a5) << 16);
  pk.w = (unsigned int)f2bf(a6) | ((unsigned int)f2bf(a7) << 16);
  *(uint4*)&AGG[(size_t)n * DD + lane16 * 8] = pk;
}

// ---------------- GRU via MFMA, 32 nodes/block (B-frags shared by 2 row-tiles) -------
__global__ __launch_bounds__(256) void k_gru(const ushort_t* __restrict__ AGG,
    ushort_t* __restrict__ HS, int l,
    const ushort_t* __restrict__ WB,
    const float* __restrict__ bih, const float* __restrict__ bhh,
    const int* __restrict__ batch, float* __restrict__ SUMS, int N) {
  __shared__ ushort_t axh[2][GNB][136];   // 17.4 KB
  __shared__ ushort_t hout[GNB][136];     // 8.7 KB
  float* SUMSQ = SUMS + GG * DD;
  int t = threadIdx.x;
  int nb = blockIdx.x * GNB;
#pragma unroll
  for (int it = 0; it < 2; ++it) {
    int n = (t >> 4) + it * 16, k8 = (t & 15) << 3;
    int gn = nb + n;
    uint4 xv = make_uint4(0, 0, 0, 0), hv = xv;
    if (gn < N) {
      xv = *(const uint4*)&AGG[(size_t)gn * DD + k8];
      hv = *(const uint4*)&HS[((size_t)gn * SS + l) * DD + k8];
    }
    *(uint4*)&axh[0][n][k8] = xv;
    *(uint4*)&axh[1][n][k8] = hv;
  }
  __syncthreads();
  int w = t >> 6, lane = t & 63, r = lane & 15, kl = lane >> 4;
  int nlast = min(nb + GNB, N) - 1;
  int bu = batch[nb];
  bool uni = (batch[nlast] == bu);
#pragma unroll
  for (int ct2 = 0; ct2 < 2; ++ct2) {
    f32x4 acc[6][2];
#pragma unroll
    for (int src = 0; src < 2; ++src) {
      bf16x8 af[2][4];
#pragma unroll
      for (int rt = 0; rt < 2; ++rt)
#pragma unroll
        for (int ks = 0; ks < 4; ++ks)
          af[rt][ks] = *(const bf16x8*)&axh[src][rt * 16 + r][ks * 32 + kl * 8];
#pragma unroll
      for (int q3 = 0; q3 < 3; ++q3) {
        int q = src * 3 + q3;
        int ctg = q * 8 + w * 2 + ct2;
        f32x4 a0 = {0.f, 0.f, 0.f, 0.f}, a1 = a0;
#pragma unroll
        for (int ks = 0; ks < 4; ++ks) {
          bf16x8 bf = *(const bf16x8*)&WB[(((size_t)ctg * 4 + ks) << 9) + (lane << 3)];
          a0 = __builtin_amdgcn_mfma_f32_16x16x32_bf16(af[0][ks], bf, a0, 0, 0, 0);
          a1 = __builtin_amdgcn_mfma_f32_16x16x32_bf16(af[1][ks], bf, a1, 0, 0, 0);
        }
        acc[q][0] = a0;
        acc[q][1] = a1;
      }
    }
    int d = w * 32 + ct2 * 16 + r;
    float br = bih[d], bz = bih[128 + d], bn2 = bih[256 + d];
    float cr = bhh[d], cz = bhh[128 + d], cn2 = bhh[256 + d];
    float loc = 0.f, locq = 0.f;
#pragma unroll
    for (int rt = 0; rt < 2; ++rt) {
#pragma unroll
      for (int i = 0; i < 4; ++i) {
        int n = rt * 16 + kl * 4 + i;
        int gn = nb + n;
        if (gn < N) {
          float gir = acc[0][rt][i] + br, giz = acc[1][rt][i] + bz, gin = acc[2][rt][i] + bn2;
          float ghr = acc[3][rt][i] + cr, ghz = acc[4][rt][i] + cz, ghn = acc[5][rt][i] + cn2;
          float rr = 1.f / (1.f + __expf(-(gir + ghr)));
          float zz = 1.f / (1.f + __expf(-(giz + ghz)));
          float nn = tanhf(gin + rr * ghn);
          float prev = bf2f(axh[1][n][d]);
          float hp = (1.f - zz) * nn + zz * prev + prev;
          hout[n][d] = f2bf(hp);
          if (uni) { loc += hp; locq += hp * hp; }
          else {
            atomicAdd(&SUMS[batch[gn] * DD + d], hp);
            atomicAdd(&SUMSQ[batch[gn] * DD + d], hp * hp);
          }
        }
      }
    }
    if (uni) {
      loc += __shfl_xor(loc, 16);
      loc += __shfl_xor(loc, 32);
      locq += __shfl_xor(locq, 16);
      locq += __shfl_xor(locq, 32);
      if (kl == 0) {
        atomicAdd(&SUMS[bu * DD + d], loc);
        atomicAdd(&SUMSQ[bu * DD + d], locq);
      }
    }
  }
  __syncthreads();
#pragma unroll
  for (int it = 0; it < 2; ++it) {
    int n = (t >> 4) + it * 16, k8 = (t & 15) << 3;
    int gn = nb + n;
    if (gn < N)
      *(uint4*)&HS[((size_t)gn * SS + l + 1) * DD + k8] = *(const uint4*)&hout[n][k8];
  }
}

// ---------------- fused GraphNorm: single pass, stats computed inline ----------------
__global__ void k_gn(ushort_t* __restrict__ HS, int slot,
    const float* __restrict__ SUMS, const int* __restrict__ CNT,
    const int* __restrict__ batch, const float* __restrict__ gms,
    const float* __restrict__ gw, const float* __restrict__ gb, int N) {
  const float* SUMSQ = SUMS + GG * DD;
  int idx = blockIdx.x * 256 + threadIdx.x;   // one thread per 8 elements
  if (idx >= N * 16) return;
  int n = idx >> 4, d0 = (idx & 15) << 3;
  int b = batch[n];
  float inv = 1.f / (float)CNT[b];
  size_t o = ((size_t)n * SS + slot) * DD + d0;
  uint4 hv = *(const uint4*)&HS[o];
  unsigned int uu[4] = {hv.x, hv.y, hv.z, hv.w};
  unsigned int out[4];
#pragma unroll
  for (int j = 0; j < 4; ++j) {
    ushort_t res[2];
#pragma unroll
    for (int k = 0; k < 2; ++k) {
      int d = d0 + j * 2 + k;
      float mean = SUMS[b * DD + d] * inv;
      float m = mean * gms[d];
      float var = SUMSQ[b * DD + d] * inv - 2.f * m * mean + m * m;
      float h = bf2f(k ? (uu[j] >> 16) : (uu[j] & 0xffffu));
      float v = (h - m) * rsqrtf(var + 1e-5f) * gw[d] + gb[d];
      res[k] = f2bf(v);
    }
    out[j] = (unsigned int)res[0] | ((unsigned int)res[1] << 16);
  }
  uint4 ov = make_uint4(out[0], out[1], out[2], out[3]);
  *(uint4*)&HS[o] = ov;
}

// ---------------- fused attention + out-proj + sum + decoder (wave-per-head) ---------
// Round-8 structure + K and V B-frag hoists (rt-invariant), NO min-waves clamp.
__global__ __launch_bounds__(256) void k_attn(const ushort_t* __restrict__ HS,
    const ushort_t* __restrict__ WI, const float* __restrict__ ipb,
    const ushort_t* __restrict__ WO, const float* __restrict__ ob,
    const ushort_t* __restrict__ WD1, const float* __restrict__ d2,
    float* __restrict__ y, int N) {
  __shared__ ushort_t hsb[64][136];        // 17.4 KB
  __shared__ ushort_t qk[4][2][16][40];    // 10.2 KB (aliased by zb after barrier)
  __shared__ ushort_t ctxb[16][136];       // 4.3 KB
  __shared__ float hss[8][132];            // 4.2 KB (aliased by ypart after barrier)
  ushort_t (*zb)[136] = (ushort_t(*)[136])&qk[0][0][0][0];
  float* ypart = &hss[0][0];
  int t = threadIdx.x;
  int nb = blockIdx.x * APB;
  // ---- stage hs (bf16), rows 8n+s, s<6 valid else 0 ----
  for (int idx = t; idx < 64 * 16; idx += 256) {
    int row = idx >> 4, k8 = (idx & 15) << 3;
    int n = row >> 3, s = row & 7;
    uint4 v = make_uint4(0, 0, 0, 0);
    if (s < 6 && nb + n < N) v = *(const uint4*)&HS[((size_t)(nb + n) * SS + s) * DD + k8];
    *(uint4*)&hsb[row][k8] = v;
  }
  __syncthreads();
  // ---- hssum[n][d] = sum_s hs ----
  {
    int n = t >> 5, d0 = (t & 31) << 2;
    float a0 = 0.f, a1 = 0.f, a2 = 0.f, a3 = 0.f;
#pragma unroll
    for (int s = 0; s < 6; ++s) {
      const ushort_t* rp = &hsb[n * 8 + s][d0];
      unsigned int u0 = *(const unsigned int*)rp;
      unsigned int u1 = *(const unsigned int*)(rp + 2);
      a0 += bf2f(u0 & 0xffffu); a1 += bf2f(u0 >> 16);
      a2 += bf2f(u1 & 0xffffu); a3 += bf2f(u1 >> 16);
    }
    hss[n][d0] = a0; hss[n][d0 + 1] = a1; hss[n][d0 + 2] = a2; hss[n][d0 + 3] = a3;
  }
  int w = t >> 6, lane = t & 63, r = lane & 15, kl = lane >> 4;
  const float sc32 = 0.17677669529663687f;  // 1/sqrt(32)
  // ---- hoist K and V B-frags (rt-invariant; LDS still caps occupancy at 4 blk/CU) ----
  bf16x8 bkh[2][4], bvh[2][4];
#pragma unroll
  for (int ct2 = 0; ct2 < 2; ++ct2)
#pragma unroll
    for (int ks = 0; ks < 4; ++ks) {
      bkh[ct2][ks] = *(const bf16x8*)&WI[(((size_t)(8 + 2 * w + ct2) * 4 + ks) << 9) + (lane << 3)];
      bvh[ct2][ks] = *(const bf16x8*)&WI[(((size_t)(16 + 2 * w + ct2) * 4 + ks) << 9) + (lane << 3)];
    }
  // ---- fused per-row-tile: qkv -> scores -> softmax -> ctx ----
#pragma unroll
  for (int rt = 0; rt < 4; ++rt) {
    bf16x8 af[4];
#pragma unroll
    for (int ks = 0; ks < 4; ++ks)
      af[ks] = *(const bf16x8*)&hsb[rt * 16 + r][ks * 32 + kl * 8];
    float vreg[2][4];
#pragma unroll
    for (int ct2 = 0; ct2 < 2; ++ct2) {
      int cq = 2 * w + ct2;
      f32x4 aq = {0.f, 0.f, 0.f, 0.f}, ak = aq, av = aq;
#pragma unroll
      for (int ks = 0; ks < 4; ++ks) {
        bf16x8 bq = *(const bf16x8*)&WI[(((size_t)cq * 4 + ks) << 9) + (lane << 3)];
        aq = __builtin_amdgcn_mfma_f32_16x16x32_bf16(af[ks], bq, aq, 0, 0, 0);
        ak = __builtin_amdgcn_mfma_f32_16x16x32_bf16(af[ks], bkh[ct2][ks], ak, 0, 0, 0);
        av = __builtin_amdgcn_mfma_f32_16x16x32_bf16(af[ks], bvh[ct2][ks], av, 0, 0, 0);
      }
      int colh = ct2 * 16 + r;
      float bq = ipb[w * 32 + colh];
      float bk = ipb[128 + w * 32 + colh];
#pragma unroll
      for (int i = 0; i < 4; ++i) {
        qk[w][0][kl * 4 + i][colh] = f2bf((aq[i] + bq) * sc32);
        qk[w][1][kl * 4 + i][colh] = f2bf(ak[i] + bk);
        vreg[ct2][i] = av[i];
      }
    }
    // scores MFMA (wave-private LDS, no barrier needed)
    bf16x8 aq = *(const bf16x8*)&qk[w][0][r][kl * 8];
    bf16x8 bk = *(const bf16x8*)&qk[w][1][r][kl * 8];
    f32x4 s4 = {0.f, 0.f, 0.f, 0.f};
    s4 = __builtin_amdgcn_mfma_f32_16x16x32_bf16(aq, bk, s4, 0, 0, 0);
    bool tval = (r & 7) < 6;
    float mx = -1e30f;
    float sc[4]; bool val[4];
#pragma unroll
    for (int i = 0; i < 4; ++i) {
      int ss = 4 * kl + i;
      val[i] = tval && (((ss ^ r) & 8) == 0) && ((ss & 7) < 6);
      sc[i] = s4[i];
      if (val[i]) mx = fmaxf(mx, sc[i]);
    }
#pragma unroll
    for (int m = 1; m <= 4; m <<= 1) mx = fmaxf(mx, __shfl_xor(mx, m));
    float e[4], sum[4];
#pragma unroll
    for (int i = 0; i < 4; ++i) {
      e[i] = val[i] ? __expf(sc[i] - mx) : 0.f;
      sum[i] = e[i];
#pragma unroll
      for (int m = 1; m <= 4; m <<= 1) sum[i] += __shfl_xor(sum[i], m);
    }
    float awp = 0.f;
#pragma unroll
    for (int i = 0; i < 4; ++i) {
      int ss = 4 * kl + i;
      float attn = (((ss & 7) < 6) && sum[i] > 0.f) ? e[i] / sum[i] : 0.f;
      awp += attn;
    }
    awp += __shfl_xor(awp, 16);
    awp += __shfl_xor(awp, 32);   // all lanes now hold aw for t-index (lane&15)
    float awv[4];
#pragma unroll
    for (int i = 0; i < 4; ++i) {
      int tt = 4 * (kl & 1) + i;
      awv[i] = __shfl(awp, (kl >> 1) * 8 + (tt < 8 ? tt : 0));
    }
    int nodei = 2 * rt + (kl >> 1);
#pragma unroll
    for (int ct2 = 0; ct2 < 2; ++ct2) {
      float acc = 0.f;
#pragma unroll
      for (int i = 0; i < 4; ++i) {
        int tt = 4 * (kl & 1) + i;
        if (tt < 6) acc += awv[i] * vreg[ct2][i];
      }
      acc += __shfl_xor(acc, 16);
      int dcol = w * 32 + ct2 * 16 + r;
      if ((kl & 1) == 0) ctxb[nodei][dcol] = f2bf(acc + 6.f * ipb[256 + dcol]);
    }
  }
  __syncthreads();   // ctxb + hss complete; qk dead -> zb alias becomes live
  // ---- phase 4: z = ctx @ WO^T + 6*ob + hssum ----
  {
    bf16x8 ac[4];
#pragma unroll
    for (int ks = 0; ks < 4; ++ks)
      ac[ks] = *(const bf16x8*)&ctxb[r][ks * 32 + kl * 8];
#pragma unroll
    for (int c2 = 0; c2 < 2; ++c2) {
      int ctg = 2 * w + c2;
      f32x4 a = {0.f, 0.f, 0.f, 0.f};
#pragma unroll
      for (int ks = 0; ks < 4; ++ks) {
        bf16x8 bf = *(const bf16x8*)&WO[(((size_t)ctg * 4 + ks) << 9) + (lane << 3)];
        a = __builtin_amdgcn_mfma_f32_16x16x32_bf16(ac[ks], bf, a, 0, 0, 0);
      }
      int col = ctg * 16 + r;
      float obv = 6.f * ob[col];
#pragma unroll
      for (int i = 0; i < 4; ++i) {
        int row = kl * 4 + i;
        float zv = (row < 8) ? (a[i] + obv + hss[row][col]) : 0.f;
        zb[row][col] = f2bf(zv);
      }
    }
  }
  __syncthreads();   // zb complete; hss dead -> ypart alias becomes live
  // ---- phase 5: decoder across all 4 waves (wave w takes d1 col-tile w) ----
  {
    bf16x8 az[4];
#pragma unroll
    for (int ks = 0; ks < 4; ++ks)
      az[ks] = *(const bf16x8*)&zb[r][ks * 32 + kl * 8];
    f32x4 a = {0.f, 0.f, 0.f, 0.f};
#pragma unroll
    for (int ks = 0; ks < 4; ++ks) {
      bf16x8 bf = *(const bf16x8*)&WD1[(((size_t)w * 4 + ks) << 9) + (lane << 3)];
      a = __builtin_amdgcn_mfma_f32_16x16x32_bf16(az[ks], bf, a, 0, 0, 0);
    }
    float dv = d2[w * 16 + r];
    float part[4];
#pragma unroll
    for (int i = 0; i < 4; ++i) {
      float u = a[i];
      u = u > 0.f ? u : 0.01f * u;
      part[i] = u * dv;
    }
#pragma unroll
    for (int m = 1; m <= 8; m <<= 1) {
#pragma unroll
      for (int i = 0; i < 4; ++i) part[i] += __shfl_xor(part[i], m);
    }
    if (r == 0) {
#pragma unroll
      for (int i = 0; i < 4; ++i) {
        int row = kl * 4 + i;
        if (row < 8) ypart[w * 8 + row] = part[i];
      }
    }
  }
  __syncthreads();
  if (t < 8) {
    float v = ypart[t] + ypart[8 + t] + ypart[16 + t] + ypart[24 + t];
    if (nb + t < N) y[nb + t] = v;
  }
}

extern "C" void kernel_launch(void* const* d_in, const int* in_sizes, int n_in,
                              void* d_out, int out_size, void* d_ws, size_t ws_size,
                              hipStream_t stream) {
  const float* x    = (const float*)d_in[0];
  const int*   ei   = (const int*)d_in[1];
  const float* norm = (const float*)d_in[2];
  const int*   batch= (const int*)d_in[3];
  const float* enc_w= (const float*)d_in[5];
  const float* wih  = (const float*)d_in[6];
  const float* whh  = (const float*)d_in[7];
  const float* bih  = (const float*)d_in[8];
  const float* bhh  = (const float*)d_in[9];
  const float* gw   = (const float*)d_in[10];
  const float* gb   = (const float*)d_in[11];
  const float* gms  = (const float*)d_in[12];
  const float* ipw  = (const float*)d_in[13];
  const float* ipb  = (const float*)d_in[14];
  const float* ow   = (const float*)d_in[15];
  const float* ob   = (const float*)d_in[16];
  const float* d1   = (const float*)d_in[17];
  const float* d2   = (const float*)d_in[18];
  float* y = (float*)d_out;
  int N = in_sizes[3];
  int E = in_sizes[2];

  char* p = (char*)d_ws;
  ushort_t* HS  = (ushort_t*)p;  p += (size_t)N * SS * DD * 2;
  ushort_t* AGG = (ushort_t*)p;  p += (size_t)N * DD * 2;
  ushort_t* WB  = (ushort_t*)p;  p += (size_t)98304 * 2;
  ushort_t* WI  = (ushort_t*)p;  p += (size_t)49152 * 2;
  ushort_t* WO  = (ushort_t*)p;  p += (size_t)16384 * 2;
  ushort_t* WD1 = (ushort_t*)p;  p += (size_t)8192 * 2;
  float* SUMS = (float*)p;       p += GG * DD * 4;   // SUMS+SUMSQ contiguous
  float* SUMSQ= (float*)p;       p += GG * DD * 4;   (void)SUMSQ;
  int*   CNT  = (int*)p;         p += GG * 4;
  int*   ENDP = (int*)p;         p += GG * 4;
  int*   BSUM = (int*)p;         p += SCB * 4;
  int*   OFF  = (int*)p;         p += ((size_t)N + 1) * 4;
  int*   CUR  = (int*)p;         p += (size_t)N * 4;
  int*   CSRS = (int*)p;         p += (size_t)E * 4;
  float* CSRN = (float*)p;

  int nchunk = (N + SCB - 1) / SCB;

  hipMemsetAsync(CUR, 0, (size_t)N * 4, stream);
  hipMemsetAsync(CNT, 0, 2 * GG * 4, stream);   // CNT + ENDP
  k_deg<<<(E + 255) / 256, 256, 0, stream>>>(ei, E, CUR);
  k_scan1<<<nchunk, SCB, 0, stream>>>(CUR, OFF, BSUM, N);
  k_scan2<<<1, SCB, 0, stream>>>(BSUM, nchunk);
  k_scan3<<<(N + 256) / 256, 256, 0, stream>>>(OFF, CUR, BSUM, batch, ENDP, N, E);
  k_fill<<<(E + 255) / 256, 256, 0, stream>>>(ei, norm, E, CUR, CSRS, CSRN);
  k_cnt<<<1, 64, 0, stream>>>(ENDP, CNT);
  k_wconv<<<672, 256, 0, stream>>>(wih, whh, ipw, ow, d1, WB, WI, WO, WD1);
  k_encode<<<(N * 64 + 255) / 256, 256, 0, stream>>>(x, enc_w, HS, N);

  for (int l = 0; l < NL; ++l) {
    k_agg<<<(N + 15) / 16, 256, 0, stream>>>(HS, l, OFF, CSRS, CSRN, AGG, SUMS, N);
    k_gru<<<(N + GNB - 1) / GNB, 256, 0, stream>>>(AGG, HS, l, WB, bih, bhh, batch, SUMS, N);
    k_gn<<<(N * 16 + 255) / 256, 256, 0, stream>>>(HS, l + 1, SUMS, CNT, batch, gms, gw, gb, N);
  }
  k_attn<<<(N + APB - 1) / APB, 256, 0, stream>>>(HS, WI, ipb, WO, ob, WD1, d2, y, N);
}

// Round 14
// 1212.056 us; speedup vs baseline: 1.0501x; 1.0501x over previous
//
#include <hip/hip_runtime.h>

#define NL 5      // num_layers (fixed by setup_inputs)
#define SS 6      // num_layers + 1
#define DD 128
#define GG 16     // NUM_GRAPHS
#define GNB 32    // nodes per block in GRU kernel
#define APB 8     // nodes per block in attention kernel
#define SCB 1024  // scan chunk

typedef __bf16 bf16x8 __attribute__((ext_vector_type(8)));
typedef float f32x4 __attribute__((ext_vector_type(4)));
typedef unsigned short ushort_t;

__device__ __forceinline__ float bf2f(unsigned int u) {
  union { unsigned int i; float f; } c; c.i = u << 16; return c.f;
}
__device__ __forceinline__ ushort_t f2bf(float f) {
  union { __bf16 b; ushort_t u; } c; c.b = (__bf16)f;  // HW v_cvt, RNE
  return c.u;
}

// ---------------- CSR build ----------------
__global__ void k_deg(const int* __restrict__ ei, int E, int* __restrict__ deg) {
  int e = blockIdx.x * 256 + threadIdx.x;
  if (e < E) atomicAdd(&deg[ei[E + e]], 1);
}

__global__ void k_scan1(const int* __restrict__ deg, int* __restrict__ off,
                        int* __restrict__ bsum, int N) {
  __shared__ int tmp[SCB];
  int t = threadIdx.x, i = blockIdx.x * SCB + t;
  int v = (i < N) ? deg[i] : 0;
  tmp[t] = v; __syncthreads();
  for (int o = 1; o < SCB; o <<= 1) {
    int a = (t >= o) ? tmp[t - o] : 0;
    __syncthreads(); tmp[t] += a; __syncthreads();
  }
  if (i < N) off[i] = tmp[t] - v;   // local exclusive
  if (t == SCB - 1) bsum[blockIdx.x] = tmp[t];
}

__global__ void k_scan2(int* __restrict__ bsum, int nb) {
  __shared__ int tmp[SCB];
  int t = threadIdx.x;
  int v = (t < nb) ? bsum[t] : 0;
  tmp[t] = v; __syncthreads();
  for (int o = 1; o < SCB; o <<= 1) {
    int a = (t >= o) ? tmp[t - o] : 0;
    __syncthreads(); tmp[t] += a; __syncthreads();
  }
  if (t < nb) bsum[t] = tmp[t] - v;  // exclusive
}

// writes final offsets to BOTH off and cur; also fused k_bend (graph end boundaries)
__global__ void k_scan3(int* __restrict__ off, int* __restrict__ cur,
                        const int* __restrict__ bsum,
                        const int* __restrict__ batch, int* __restrict__ endp,
                        int N, int E) {
  int i = blockIdx.x * 256 + threadIdx.x;
  if (i < N) {
    int v = off[i] + bsum[i >> 10];
    off[i] = v;
    cur[i] = v;
    int b = batch[i];
    if (i == N - 1 || batch[i + 1] != b) endp[b] = i + 1;
  } else if (i == N) off[N] = E;
}

__global__ void k_fill(const int* __restrict__ ei, const float* __restrict__ norm, int E,
                       int* __restrict__ cur, int* __restrict__ csrs, float* __restrict__ csrn) {
  int e = blockIdx.x * 256 + threadIdx.x;
  if (e >= E) return;
  int s = ei[e], d = ei[E + e];
  int p = atomicAdd(&cur[d], 1);
  csrs[p] = s;
  csrn[p] = norm[e];
}

__global__ void k_cnt(const int* __restrict__ endp, int* __restrict__ cnt) {
  if (threadIdx.x == 0 && blockIdx.x == 0) {
    int prev = 0;
    for (int g = 0; g < GG; ++g) {
      int e = endp[g];
      if (e > prev) { cnt[g] = e - prev; prev = e; }
      else cnt[g] = 0;
    }
  }
}

// ---------------- weight conversion + B-fragment swizzle ----------------
// B-frag order: out[((ctg*4 + ks)*64 + lane)*8 + j] = W[ctg*16 + (lane&15)][ks*32 + ((lane>>4)<<3) + j]
__global__ void k_wconv(const float* __restrict__ wih, const float* __restrict__ whh,
                        const float* __restrict__ ipw, const float* __restrict__ ow,
                        const float* __restrict__ d1,
                        ushort_t* __restrict__ WB, ushort_t* __restrict__ WI,
                        ushort_t* __restrict__ WO, ushort_t* __restrict__ WD1) {
  int o = blockIdx.x * 256 + threadIdx.x;
  int seg, idx;
  if (o < 98304) { seg = 0; idx = o; }
  else if (o < 98304 + 49152) { seg = 1; idx = o - 98304; }
  else if (o < 98304 + 49152 + 16384) { seg = 2; idx = o - 98304 - 49152; }
  else if (o < 98304 + 49152 + 16384 + 8192) { seg = 3; idx = o - 98304 - 49152 - 16384; }
  else return;
  int j = idx & 7, l = (idx >> 3) & 63, ks = (idx >> 9) & 3, ctg = idx >> 11;
  int row = ctg * 16 + (l & 15);
  int col = ks * 32 + ((l >> 4) << 3) + j;
  float v;
  if (seg == 0) { v = (row < 384) ? wih[row * 128 + col] : whh[(row - 384) * 128 + col]; WB[idx] = f2bf(v); }
  else if (seg == 1) { WI[idx] = f2bf(ipw[row * 128 + col]); }
  else if (seg == 2) { WO[idx] = f2bf(ow[row * 128 + col]); }
  else { WD1[idx] = f2bf(d1[row * 128 + col]); }
}

// ---------------- encoder (2 dims/thread, dword stores) ----------------
__global__ void k_encode(const float* __restrict__ x, const float* __restrict__ ew,
                         ushort_t* __restrict__ HS, int N) {
  int idx = blockIdx.x * 256 + threadIdx.x;
  if (idx >= N * 64) return;
  int n = idx >> 6, d0 = (idx & 63) << 1;
  float xr[6];
#pragma unroll
  for (int k = 0; k < 6; ++k) xr[k] = x[n * 6 + k];
  float a0 = 0.f, a1 = 0.f;
#pragma unroll
  for (int k = 0; k < 6; ++k) {
    a0 += xr[k] * ew[d0 * 6 + k];
    a1 += xr[k] * ew[(d0 + 1) * 6 + k];
  }
  a0 = a0 > 0.f ? a0 : 0.01f * a0;
  a1 = a1 > 0.f ? a1 : 0.01f * a1;
  unsigned int pk = (unsigned int)f2bf(a0) | ((unsigned int)f2bf(a1) << 16);
  *(unsigned int*)&HS[((size_t)n * SS) * DD + d0] = pk;
}

// ---------------- aggregation: 4 nodes/wave (16 lanes x 8 bf16 via uint4), 8-deep ILP
// block 0 also zeroes SUMS+SUMSQ (contiguous, 2*GG*DD floats) for this layer
__global__ __launch_bounds__(256) void k_agg(const ushort_t* __restrict__ HS, int l,
    const int* __restrict__ off, const int* __restrict__ csrs, const float* __restrict__ csrn,
    ushort_t* __restrict__ AGG, float* __restrict__ SUMS, int N) {
  if (blockIdx.x == 0) {
    for (int i = threadIdx.x; i < 2 * GG * DD; i += 256) SUMS[i] = 0.f;
  }
  int n = blockIdx.x * 16 + (threadIdx.x >> 4);
  if (n >= N) return;
  int lane16 = threadIdx.x & 15;
  int p0 = off[n], p1 = off[n + 1];
  float a0 = 0.f, a1 = 0.f, a2 = 0.f, a3 = 0.f, a4 = 0.f, a5 = 0.f, a6 = 0.f, a7 = 0.f;
  const ushort_t* base = HS + l * DD + lane16 * 8;
  int p = p0;
  for (; p + 8 <= p1; p += 8) {
    int s[8]; float w[8]; uint4 u[8];
#pragma unroll
    for (int q = 0; q < 8; ++q) { s[q] = csrs[p + q]; w[q] = csrn[p + q]; }
#pragma unroll
    for (int q = 0; q < 8; ++q) u[q] = *(const uint4*)(base + (size_t)s[q] * (SS * DD));
#pragma unroll
    for (int q = 0; q < 8; ++q) {
      a0 += w[q] * bf2f(u[q].x & 0xffffu);
      a1 += w[q] * bf2f(u[q].x >> 16);
      a2 += w[q] * bf2f(u[q].y & 0xffffu);
      a3 += w[q] * bf2f(u[q].y >> 16);
      a4 += w[q] * bf2f(u[q].z & 0xffffu);
      a5 += w[q] * bf2f(u[q].z >> 16);
      a6 += w[q] * bf2f(u[q].w & 0xffffu);
      a7 += w[q] * bf2f(u[q].w >> 16);
    }
  }
  for (; p < p1; ++p) {
    int s0 = csrs[p];
    float w0 = csrn[p];
    uint4 u0 = *(const uint4*)(base + (size_t)s0 * (SS * DD));
    a0 += w0 * bf2f(u0.x & 0xffffu);
    a1 += w0 * bf2f(u0.x >> 16);
    a2 += w0 * bf2f(u0.y & 0xffffu);
    a3 += w0 * bf2f(u0.y >> 16);
    a4 += w0 * bf2f(u0.z & 0xffffu);
    a5 += w0 * bf2f(u0.z >> 16);
    a6 += w0 * bf2f(u0.w & 0xffffu);
    a7 += w0 * bf2f(u0.w >> 16);
  }
  uint4 pk;
  pk.x = (unsigned int)f2bf(a0) | ((unsigned int)f2bf(a1) << 16);
  pk.y = (unsigned int)f2bf(a2) | ((unsigned int)f2bf(a3) << 16);
  pk.z = (unsigned int)f2bf(a4) | ((unsigned int)f2bf(a5) << 16);
  pk.w = (unsigned int)f2bf(a6) | ((unsigned int)f2bf(a7) << 16);
  *(uint4*)&AGG[(size_t)n * DD + lane16 * 8] = pk;
}

// ---------------- GRU via MFMA, 32 nodes/block (B-frags shared by 2 row-tiles) -------
__global__ __launch_bounds__(256) void k_gru(const ushort_t* __restrict__ AGG,
    ushort_t* __restrict__ HS, int l,
    const ushort_t* __restrict__ WB,
    const float* __restrict__ bih, const float* __restrict__ bhh,
    const int* __restrict__ batch, float* __restrict__ SUMS, int N) {
  __shared__ ushort_t axh[2][GNB][136];   // 17.4 KB
  __shared__ ushort_t hout[GNB][136];     // 8.7 KB
  float* SUMSQ = SUMS + GG * DD;
  int t = threadIdx.x;
  int nb = blockIdx.x * GNB;
#pragma unroll
  for (int it = 0; it < 2; ++it) {
    int n = (t >> 4) + it * 16, k8 = (t & 15) << 3;
    int gn = nb + n;
    uint4 xv = make_uint4(0, 0, 0, 0), hv = xv;
    if (gn < N) {
      xv = *(const uint4*)&AGG[(size_t)gn * DD + k8];
      hv = *(const uint4*)&HS[((size_t)gn * SS + l) * DD + k8];
    }
    *(uint4*)&axh[0][n][k8] = xv;
    *(uint4*)&axh[1][n][k8] = hv;
  }
  __syncthreads();
  int w = t >> 6, lane = t & 63, r = lane & 15, kl = lane >> 4;
  int nlast = min(nb + GNB, N) - 1;
  int bu = batch[nb];
  bool uni = (batch[nlast] == bu);
#pragma unroll
  for (int ct2 = 0; ct2 < 2; ++ct2) {
    f32x4 acc[6][2];
#pragma unroll
    for (int src = 0; src < 2; ++src) {
      bf16x8 af[2][4];
#pragma unroll
      for (int rt = 0; rt < 2; ++rt)
#pragma unroll
        for (int ks = 0; ks < 4; ++ks)
          af[rt][ks] = *(const bf16x8*)&axh[src][rt * 16 + r][ks * 32 + kl * 8];
#pragma unroll
      for (int q3 = 0; q3 < 3; ++q3) {
        int q = src * 3 + q3;
        int ctg = q * 8 + w * 2 + ct2;
        f32x4 a0 = {0.f, 0.f, 0.f, 0.f}, a1 = a0;
#pragma unroll
        for (int ks = 0; ks < 4; ++ks) {
          bf16x8 bf = *(const bf16x8*)&WB[(((size_t)ctg * 4 + ks) << 9) + (lane << 3)];
          a0 = __builtin_amdgcn_mfma_f32_16x16x32_bf16(af[0][ks], bf, a0, 0, 0, 0);
          a1 = __builtin_amdgcn_mfma_f32_16x16x32_bf16(af[1][ks], bf, a1, 0, 0, 0);
        }
        acc[q][0] = a0;
        acc[q][1] = a1;
      }
    }
    int d = w * 32 + ct2 * 16 + r;
    float br = bih[d], bz = bih[128 + d], bn2 = bih[256 + d];
    float cr = bhh[d], cz = bhh[128 + d], cn2 = bhh[256 + d];
    float loc = 0.f, locq = 0.f;
#pragma unroll
    for (int rt = 0; rt < 2; ++rt) {
#pragma unroll
      for (int i = 0; i < 4; ++i) {
        int n = rt * 16 + kl * 4 + i;
        int gn = nb + n;
        if (gn < N) {
          float gir = acc[0][rt][i] + br, giz = acc[1][rt][i] + bz, gin = acc[2][rt][i] + bn2;
          float ghr = acc[3][rt][i] + cr, ghz = acc[4][rt][i] + cz, ghn = acc[5][rt][i] + cn2;
          float rr = 1.f / (1.f + __expf(-(gir + ghr)));
          float zz = 1.f / (1.f + __expf(-(giz + ghz)));
          float nn = tanhf(gin + rr * ghn);
          float prev = bf2f(axh[1][n][d]);
          float hp = (1.f - zz) * nn + zz * prev + prev;
          hout[n][d] = f2bf(hp);
          if (uni) { loc += hp; locq += hp * hp; }
          else {
            atomicAdd(&SUMS[batch[gn] * DD + d], hp);
            atomicAdd(&SUMSQ[batch[gn] * DD + d], hp * hp);
          }
        }
      }
    }
    if (uni) {
      loc += __shfl_xor(loc, 16);
      loc += __shfl_xor(loc, 32);
      locq += __shfl_xor(locq, 16);
      locq += __shfl_xor(locq, 32);
      if (kl == 0) {
        atomicAdd(&SUMS[bu * DD + d], loc);
        atomicAdd(&SUMSQ[bu * DD + d], locq);
      }
    }
  }
  __syncthreads();
#pragma unroll
  for (int it = 0; it < 2; ++it) {
    int n = (t >> 4) + it * 16, k8 = (t & 15) << 3;
    int gn = nb + n;
    if (gn < N)
      *(uint4*)&HS[((size_t)gn * SS + l + 1) * DD + k8] = *(const uint4*)&hout[n][k8];
  }
}

// ---------------- fused GraphNorm: single pass, stats computed inline ----------------
__global__ void k_gn(ushort_t* __restrict__ HS, int slot,
    const float* __restrict__ SUMS, const int* __restrict__ CNT,
    const int* __restrict__ batch, const float* __restrict__ gms,
    const float* __restrict__ gw, const float* __restrict__ gb, int N) {
  const float* SUMSQ = SUMS + GG * DD;
  int idx = blockIdx.x * 256 + threadIdx.x;   // one thread per 8 elements
  if (idx >= N * 16) return;
  int n = idx >> 4, d0 = (idx & 15) << 3;
  int b = batch[n];
  float inv = 1.f / (float)CNT[b];
  size_t o = ((size_t)n * SS + slot) * DD + d0;
  uint4 hv = *(const uint4*)&HS[o];
  unsigned int uu[4] = {hv.x, hv.y, hv.z, hv.w};
  unsigned int out[4];
#pragma unroll
  for (int j = 0; j < 4; ++j) {
    ushort_t res[2];
#pragma unroll
    for (int k = 0; k < 2; ++k) {
      int d = d0 + j * 2 + k;
      float mean = SUMS[b * DD + d] * inv;
      float m = mean * gms[d];
      float var = SUMSQ[b * DD + d] * inv - 2.f * m * mean + m * m;
      float h = bf2f(k ? (uu[j] >> 16) : (uu[j] & 0xffffu));
      float v = (h - m) * rsqrtf(var + 1e-5f) * gw[d] + gb[d];
      res[k] = f2bf(v);
    }
    out[j] = (unsigned int)res[0] | ((unsigned int)res[1] << 16);
  }
  uint4 ov = make_uint4(out[0], out[1], out[2], out[3]);
  *(uint4*)&HS[o] = ov;
}

// ---------------- fused attention + out-proj + sum + decoder (wave-per-head) ---------
// Round-12 proven config: hsb staging + V B-frag hoist only, NO min-waves clamp.
__global__ __launch_bounds__(256) void k_attn(const ushort_t* __restrict__ HS,
    const ushort_t* __restrict__ WI, const float* __restrict__ ipb,
    const ushort_t* __restrict__ WO, const float* __restrict__ ob,
    const ushort_t* __restrict__ WD1, const float* __restrict__ d2,
    float* __restrict__ y, int N) {
  __shared__ ushort_t hsb[64][136];        // 17.4 KB
  __shared__ ushort_t qk[4][2][16][40];    // 10.2 KB (aliased by zb after barrier)
  __shared__ ushort_t ctxb[16][136];       // 4.3 KB
  __shared__ float hss[8][132];            // 4.2 KB (aliased by ypart after barrier)
  ushort_t (*zb)[136] = (ushort_t(*)[136])&qk[0][0][0][0];
  float* ypart = &hss[0][0];
  int t = threadIdx.x;
  int nb = blockIdx.x * APB;
  // ---- stage hs (bf16), rows 8n+s, s<6 valid else 0 ----
  for (int idx = t; idx < 64 * 16; idx += 256) {
    int row = idx >> 4, k8 = (idx & 15) << 3;
    int n = row >> 3, s = row & 7;
    uint4 v = make_uint4(0, 0, 0, 0);
    if (s < 6 && nb + n < N) v = *(const uint4*)&HS[((size_t)(nb + n) * SS + s) * DD + k8];
    *(uint4*)&hsb[row][k8] = v;
  }
  __syncthreads();
  // ---- hssum[n][d] = sum_s hs ----
  {
    int n = t >> 5, d0 = (t & 31) << 2;
    float a0 = 0.f, a1 = 0.f, a2 = 0.f, a3 = 0.f;
#pragma unroll
    for (int s = 0; s < 6; ++s) {
      const ushort_t* rp = &hsb[n * 8 + s][d0];
      unsigned int u0 = *(const unsigned int*)rp;
      unsigned int u1 = *(const unsigned int*)(rp + 2);
      a0 += bf2f(u0 & 0xffffu); a1 += bf2f(u0 >> 16);
      a2 += bf2f(u1 & 0xffffu); a3 += bf2f(u1 >> 16);
    }
    hss[n][d0] = a0; hss[n][d0 + 1] = a1; hss[n][d0 + 2] = a2; hss[n][d0 + 3] = a3;
  }
  int w = t >> 6, lane = t & 63, r = lane & 15, kl = lane >> 4;
  const float sc32 = 0.17677669529663687f;  // 1/sqrt(32)
  // ---- hoist V B-frags (rt-invariant; fits existing VGPR budget) ----
  bf16x8 bvh[2][4];
#pragma unroll
  for (int ct2 = 0; ct2 < 2; ++ct2)
#pragma unroll
    for (int ks = 0; ks < 4; ++ks)
      bvh[ct2][ks] = *(const bf16x8*)&WI[(((size_t)(16 + 2 * w + ct2) * 4 + ks) << 9) + (lane << 3)];
  // ---- fused per-row-tile: qkv -> scores -> softmax -> ctx ----
#pragma unroll
  for (int rt = 0; rt < 4; ++rt) {
    bf16x8 af[4];
#pragma unroll
    for (int ks = 0; ks < 4; ++ks)
      af[ks] = *(const bf16x8*)&hsb[rt * 16 + r][ks * 32 + kl * 8];
    float vreg[2][4];
#pragma unroll
    for (int ct2 = 0; ct2 < 2; ++ct2) {
      int cq = 2 * w + ct2, ck = 8 + 2 * w + ct2;
      f32x4 aq = {0.f, 0.f, 0.f, 0.f}, ak = aq, av = aq;
#pragma unroll
      for (int ks = 0; ks < 4; ++ks) {
        bf16x8 bq = *(const bf16x8*)&WI[(((size_t)cq * 4 + ks) << 9) + (lane << 3)];
        bf16x8 bk = *(const bf16x8*)&WI[(((size_t)ck * 4 + ks) << 9) + (lane << 3)];
        aq = __builtin_amdgcn_mfma_f32_16x16x32_bf16(af[ks], bq, aq, 0, 0, 0);
        ak = __builtin_amdgcn_mfma_f32_16x16x32_bf16(af[ks], bk, ak, 0, 0, 0);
        av = __builtin_amdgcn_mfma_f32_16x16x32_bf16(af[ks], bvh[ct2][ks], av, 0, 0, 0);
      }
      int colh = ct2 * 16 + r;
      float bq = ipb[w * 32 + colh];
      float bk = ipb[128 + w * 32 + colh];
#pragma unroll
      for (int i = 0; i < 4; ++i) {
        qk[w][0][kl * 4 + i][colh] = f2bf((aq[i] + bq) * sc32);
        qk[w][1][kl * 4 + i][colh] = f2bf(ak[i] + bk);
        vreg[ct2][i] = av[i];
      }
    }
    // scores MFMA (wave-private LDS, no barrier needed)
    bf16x8 aq = *(const bf16x8*)&qk[w][0][r][kl * 8];
    bf16x8 bk = *(const bf16x8*)&qk[w][1][r][kl * 8];
    f32x4 s4 = {0.f, 0.f, 0.f, 0.f};
    s4 = __builtin_amdgcn_mfma_f32_16x16x32_bf16(aq, bk, s4, 0, 0, 0);
    bool tval = (r & 7) < 6;
    float mx = -1e30f;
    float sc[4]; bool val[4];
#pragma unroll
    for (int i = 0; i < 4; ++i) {
      int ss = 4 * kl + i;
      val[i] = tval && (((ss ^ r) & 8) == 0) && ((ss & 7) < 6);
      sc[i] = s4[i];
      if (val[i]) mx = fmaxf(mx, sc[i]);
    }
#pragma unroll
    for (int m = 1; m <= 4; m <<= 1) mx = fmaxf(mx, __shfl_xor(mx, m));
    float e[4], sum[4];
#pragma unroll
    for (int i = 0; i < 4; ++i) {
      e[i] = val[i] ? __expf(sc[i] - mx) : 0.f;
      sum[i] = e[i];
#pragma unroll
      for (int m = 1; m <= 4; m <<= 1) sum[i] += __shfl_xor(sum[i], m);
    }
    float awp = 0.f;
#pragma unroll
    for (int i = 0; i < 4; ++i) {
      int ss = 4 * kl + i;
      float attn = (((ss & 7) < 6) && sum[i] > 0.f) ? e[i] / sum[i] : 0.f;
      awp += attn;
    }
    awp += __shfl_xor(awp, 16);
    awp += __shfl_xor(awp, 32);   // all lanes now hold aw for t-index (lane&15)
    float awv[4];
#pragma unroll
    for (int i = 0; i < 4; ++i) {
      int tt = 4 * (kl & 1) + i;
      awv[i] = __shfl(awp, (kl >> 1) * 8 + (tt < 8 ? tt : 0));
    }
    int nodei = 2 * rt + (kl >> 1);
#pragma unroll
    for (int ct2 = 0; ct2 < 2; ++ct2) {
      float acc = 0.f;
#pragma unroll
      for (int i = 0; i < 4; ++i) {
        int tt = 4 * (kl & 1) + i;
        if (tt < 6) acc += awv[i] * vreg[ct2][i];
      }
      acc += __shfl_xor(acc, 16);
      int dcol = w * 32 + ct2 * 16 + r;
      if ((kl & 1) == 0) ctxb[nodei][dcol] = f2bf(acc + 6.f * ipb[256 + dcol]);
    }
  }
  __syncthreads();   // ctxb + hss complete; qk dead -> zb alias becomes live
  // ---- phase 4: z = ctx @ WO^T + 6*ob + hssum ----
  {
    bf16x8 ac[4];
#pragma unroll
    for (int ks = 0; ks < 4; ++ks)
      ac[ks] = *(const bf16x8*)&ctxb[r][ks * 32 + kl * 8];
#pragma unroll
    for (int c2 = 0; c2 < 2; ++c2) {
      int ctg = 2 * w + c2;
      f32x4 a = {0.f, 0.f, 0.f, 0.f};
#pragma unroll
      for (int ks = 0; ks < 4; ++ks) {
        bf16x8 bf = *(const bf16x8*)&WO[(((size_t)ctg * 4 + ks) << 9) + (lane << 3)];
        a = __builtin_amdgcn_mfma_f32_16x16x32_bf16(ac[ks], bf, a, 0, 0, 0);
      }
      int col = ctg * 16 + r;
      float obv = 6.f * ob[col];
#pragma unroll
      for (int i = 0; i < 4; ++i) {
        int row = kl * 4 + i;
        float zv = (row < 8) ? (a[i] + obv + hss[row][col]) : 0.f;
        zb[row][col] = f2bf(zv);
      }
    }
  }
  __syncthreads();   // zb complete; hss dead -> ypart alias becomes live
  // ---- phase 5: decoder across all 4 waves (wave w takes d1 col-tile w) ----
  {
    bf16x8 az[4];
#pragma unroll
    for (int ks = 0; ks < 4; ++ks)
      az[ks] = *(const bf16x8*)&zb[r][ks * 32 + kl * 8];
    f32x4 a = {0.f, 0.f, 0.f, 0.f};
#pragma unroll
    for (int ks = 0; ks < 4; ++ks) {
      bf16x8 bf = *(const bf16x8*)&WD1[(((size_t)w * 4 + ks) << 9) + (lane << 3)];
      a = __builtin_amdgcn_mfma_f32_16x16x32_bf16(az[ks], bf, a, 0, 0, 0);
    }
    float dv = d2[w * 16 + r];
    float part[4];
#pragma unroll
    for (int i = 0; i < 4; ++i) {
      float u = a[i];
      u = u > 0.f ? u : 0.01f * u;
      part[i] = u * dv;
    }
#pragma unroll
    for (int m = 1; m <= 8; m <<= 1) {
#pragma unroll
      for (int i = 0; i < 4; ++i) part[i] += __shfl_xor(part[i], m);
    }
    if (r == 0) {
#pragma unroll
      for (int i = 0; i < 4; ++i) {
        int row = kl * 4 + i;
        if (row < 8) ypart[w * 8 + row] = part[i];
      }
    }
  }
  __syncthreads();
  if (t < 8) {
    float v = ypart[t] + ypart[8 + t] + ypart[16 + t] + ypart[24 + t];
    if (nb + t < N) y[nb + t] = v;
  }
}

extern "C" void kernel_launch(void* const* d_in, const int* in_sizes, int n_in,
                              void* d_out, int out_size, void* d_ws, size_t ws_size,
                              hipStream_t stream) {
  const float* x    = (const float*)d_in[0];
  const int*   ei   = (const int*)d_in[1];
  const float* norm = (const float*)d_in[2];
  const int*   batch= (const int*)d_in[3];
  const float* enc_w= (const float*)d_in[5];
  const float* wih  = (const float*)d_in[6];
  const float* whh  = (const float*)d_in[7];
  const float* bih  = (const float*)d_in[8];
  const float* bhh  = (const float*)d_in[9];
  const float* gw   = (const float*)d_in[10];
  const float* gb   = (const float*)d_in[11];
  const float* gms  = (const float*)d_in[12];
  const float* ipw  = (const float*)d_in[13];
  const float* ipb  = (const float*)d_in[14];
  const float* ow   = (const float*)d_in[15];
  const float* ob   = (const float*)d_in[16];
  const float* d1   = (const float*)d_in[17];
  const float* d2   = (const float*)d_in[18];
  float* y = (float*)d_out;
  int N = in_sizes[3];
  int E = in_sizes[2];

  char* p = (char*)d_ws;
  ushort_t* HS  = (ushort_t*)p;  p += (size_t)N * SS * DD * 2;
  ushort_t* AGG = (ushort_t*)p;  p += (size_t)N * DD * 2;
  ushort_t* WB  = (ushort_t*)p;  p += (size_t)98304 * 2;
  ushort_t* WI  = (ushort_t*)p;  p += (size_t)49152 * 2;
  ushort_t* WO  = (ushort_t*)p;  p += (size_t)16384 * 2;
  ushort_t* WD1 = (ushort_t*)p;  p += (size_t)8192 * 2;
  float* SUMS = (float*)p;       p += GG * DD * 4;   // SUMS+SUMSQ contiguous
  float* SUMSQ= (float*)p;       p += GG * DD * 4;   (void)SUMSQ;
  int*   CNT  = (int*)p;         p += GG * 4;
  int*   ENDP = (int*)p;         p += GG * 4;
  int*   BSUM = (int*)p;         p += SCB * 4;
  int*   OFF  = (int*)p;         p += ((size_t)N + 1) * 4;
  int*   CUR  = (int*)p;         p += (size_t)N * 4;
  int*   CSRS = (int*)p;         p += (size_t)E * 4;
  float* CSRN = (float*)p;

  int nchunk = (N + SCB - 1) / SCB;

  hipMemsetAsync(CUR, 0, (size_t)N * 4, stream);
  hipMemsetAsync(CNT, 0, 2 * GG * 4, stream);   // CNT + ENDP
  k_deg<<<(E + 255) / 256, 256, 0, stream>>>(ei, E, CUR);
  k_scan1<<<nchunk, SCB, 0, stream>>>(CUR, OFF, BSUM, N);
  k_scan2<<<1, SCB, 0, stream>>>(BSUM, nchunk);
  k_scan3<<<(N + 256) / 256, 256, 0, stream>>>(OFF, CUR, BSUM, batch, ENDP, N, E);
  k_fill<<<(E + 255) / 256, 256, 0, stream>>>(ei, norm, E, CUR, CSRS, CSRN);
  k_cnt<<<1, 64, 0, stream>>>(ENDP, CNT);
  k_wconv<<<672, 256, 0, stream>>>(wih, whh, ipw, ow, d1, WB, WI, WO, WD1);
  k_encode<<<(N * 64 + 255) / 256, 256, 0, stream>>>(x, enc_w, HS, N);

  for (int l = 0; l < NL; ++l) {
    k_agg<<<(N + 15) / 16, 256, 0, stream>>>(HS, l, OFF, CSRS, CSRN, AGG, SUMS, N);
    k_gru<<<(N + GNB - 1) / GNB, 256, 0, stream>>>(AGG, HS, l, WB, bih, bhh, batch, SUMS, N);
    k_gn<<<(N * 16 + 255) / 256, 256, 0, stream>>>(HS, l + 1, SUMS, CNT, batch, gms, gw, gb, N);
  }
  k_attn<<<(N + APB - 1) / APB, 256, 0, stream>>>(HS, WI, ipb, WO, ob, WD1, d2, y, N);
}